// Round 6
// baseline (2260.879 us; speedup 1.0000x reference)
//
#include <hip/hip_runtime.h>
#include <stdint.h>

#define NW 254

typedef float f32x4 __attribute__((ext_vector_type(4)));
typedef __bf16 bf16x8 __attribute__((ext_vector_type(8)));

__device__ __forceinline__ unsigned short f2bf(float f){
  union { float f; unsigned int i; } v; v.f = f;
  unsigned int r = (v.i + 0x7FFFu + ((v.i >> 16) & 1u)) >> 16;
  return (unsigned short)r;
}
__device__ __forceinline__ float sigmoidf_(float x){ return 1.0f / (1.0f + __expf(-x)); }
__device__ __forceinline__ float tanhf_(float x){ return 1.0f - 2.0f / (__expf(2.0f * x) + 1.0f); }

__device__ __forceinline__ float fp8_to_f32(unsigned int b){
#if __has_builtin(__builtin_amdgcn_cvt_f32_fp8)
  return __builtin_amdgcn_cvt_f32_fp8(b, 0);
#else
  unsigned int s = b >> 7, e = (b >> 3) & 15, m = b & 7;
  float v;
  if (e == 0) v = (float)m * 0.001953125f;
  else        v = ldexpf((float)(8 + m), (int)e - 10);
  return s ? -v : v;
#endif
}

// ---------------- diagnostic ----------------
__global__ void k_diag(float* out, float v){
  if (threadIdx.x < 10) out[threadIdx.x] = v;
}

// ---------------- prep: W[N,256] f32 -> fp8 frags x8 scale ----------------
// dst[mod][nt][kt][lane] u64; byte j = fp8(8*W[nt*16+(l&15)][kt*32+(l>>4)*8+j])
__global__ void k_wcvt(const float* W0, const float* W1, const float* W2,
                       unsigned long long* dst, int NT){
  int gid = blockIdx.x * 256 + threadIdx.x;
  int per_mod = NT * 8 * 64;
  int mod = gid / per_mod;
  if (mod >= 3) return;
  int r = gid % per_mod;
  int nt = r / 512; int r2 = r % 512;
  int kt = r2 >> 6; int lane = r2 & 63;
  const float* W = (mod == 0) ? W0 : ((mod == 1) ? W1 : W2);
  int n = nt * 16 + (lane & 15);
  int k = kt * 32 + (lane >> 4) * 8;
  const float* p = W + (size_t)n * 256 + k;
  int lo = __builtin_amdgcn_cvt_pk_fp8_f32(8.f*p[0], 8.f*p[1], 0, false);
  lo     = __builtin_amdgcn_cvt_pk_fp8_f32(8.f*p[2], 8.f*p[3], lo, true);
  int hi = __builtin_amdgcn_cvt_pk_fp8_f32(8.f*p[4], 8.f*p[5], 0, false);
  hi     = __builtin_amdgcn_cvt_pk_fp8_f32(8.f*p[6], 8.f*p[7], hi, true);
  dst[gid] = ((unsigned long long)(unsigned int)hi << 32) | (unsigned int)lo;
}

__global__ void k_bias(const float* v1, const float* v2, const float* a1, const float* a2,
                       const float* t1, const float* t2, float* dst){
  int gid = blockIdx.x * 256 + threadIdx.x;
  if (gid >= 3072) return;
  int mod = gid >> 10, n = gid & 1023;
  const float* p1 = (mod == 0) ? v1 : ((mod == 1) ? a1 : t1);
  const float* p2 = (mod == 0) ? v2 : ((mod == 1) ? a2 : t2);
  dst[gid] = p1[n] + p2[n];
}

// ---------------- fused xg + LSTM + pred (chunk of 8 steps) ----------------
// 192 blocks: mod = blk>>6, row-pair rp = blk&63 (batch rows 2rp, 2rp+1).
// Whh fp8 frags VGPR-resident; xg computed in-registers; pred -> fp8 ring.
__global__ __launch_bounds__(512, 1) void k_lstm(
    const unsigned long long* wihf, const unsigned long long* whhf,
    const unsigned long long* wpf, const float* biasg,
    const float* xv, const float* xa, const float* xt,
    const float* bpv, const float* bpa, const float* bpt,
    float* cstate, unsigned char* hstate, unsigned char* ring, int t0)
{
  const int blk = blockIdx.x;
  const int mod = blk >> 6;
  const int b0  = (blk & 63) * 2;
  const int tid = threadIdx.x;
  const int w   = tid >> 6;
  const int lane = tid & 63;
  const int l15 = lane & 15, lq = lane >> 4;

  __shared__ __align__(16) unsigned char hist[9][2][256];  // h*16 fp8, hist[0]=carry-in
  __shared__ __align__(16) float gbuf[1024][2];

  const float* xsel  = (mod == 0) ? xv  : ((mod == 1) ? xa  : xt);
  const float* bpsel = (mod == 0) ? bpv : ((mod == 1) ? bpa : bpt);

  // state init (thread owns (row=tid>>8, q=tid&255))
  const int srow = tid >> 8, sq = tid & 255;
  hist[0][srow][sq] = (t0 == 0) ? (unsigned char)0
      : hstate[((size_t)mod * 128 + b0 + srow) * 256 + sq];
  float creg = (t0 == 0) ? 0.f
      : cstate[((size_t)mod * 128 + b0 + srow) * 256 + sq];

  // Whh frags resident: wave w owns gate cols [128w, 128w+128)
  unsigned long long wfr[8][8];
  {
    const unsigned long long* src = whhf + (size_t)mod * 32768 + w * 4096 + lane;
    #pragma unroll
    for (int nl = 0; nl < 8; nl++)
      #pragma unroll
      for (int kt = 0; kt < 8; kt++)
        wfr[nl][kt] = src[(nl * 8 + kt) * 64];
  }

  // A-frags for xg: row ra=l15 -> (tl=ra>>1, br=ra&1); x fp8 unscaled
  unsigned long long afr[8];
  {
    const float* xp = xsel + ((size_t)(b0 + (l15 & 1)) * 256 + (t0 + (l15 >> 1))) * 256;
    #pragma unroll
    for (int kt = 0; kt < 8; kt++){
      float4 va = *(const float4*)(xp + kt * 32 + lq * 8);
      float4 vb = *(const float4*)(xp + kt * 32 + lq * 8 + 4);
      int lo = __builtin_amdgcn_cvt_pk_fp8_f32(va.x, va.y, 0, false);
      lo     = __builtin_amdgcn_cvt_pk_fp8_f32(va.z, va.w, lo, true);
      int hi = __builtin_amdgcn_cvt_pk_fp8_f32(vb.x, vb.y, 0, false);
      hi     = __builtin_amdgcn_cvt_pk_fp8_f32(vb.z, vb.w, hi, true);
      afr[kt] = ((unsigned long long)(unsigned int)hi << 32) | (unsigned int)lo;
    }
  }

  // xg GEMM: xga[nl][r] = XG[row=lq*4+r][col=(w*8+nl)*16+l15] (scaled back, +bias)
  f32x4 xga[8];
  {
    const unsigned long long* bsrc = wihf + (size_t)mod * 32768 + w * 4096 + lane;
    #pragma unroll
    for (int nl = 0; nl < 8; nl++){
      f32x4 acc = (f32x4){0.f, 0.f, 0.f, 0.f};
      #pragma unroll
      for (int kt = 0; kt < 8; kt++)
        acc = __builtin_amdgcn_mfma_f32_16x16x32_fp8_fp8(
            (long long)afr[kt], (long long)bsrc[(nl * 8 + kt) * 64], acc, 0, 0, 0);
      float bg = biasg[mod * 1024 + (w * 8 + nl) * 16 + l15];
      #pragma unroll
      for (int r = 0; r < 4; r++) xga[nl][r] = acc[r] * 0.125f + bg;
    }
  }
  __syncthreads();  // hist[0] ready

  // recurrence: 8 steps
  #pragma unroll
  for (int tl = 0; tl < 8; tl++){
    f32x4 racc[8];
    #pragma unroll
    for (int nl = 0; nl < 8; nl++) racc[nl] = (f32x4){0.f, 0.f, 0.f, 0.f};
    #pragma unroll
    for (int kt = 0; kt < 8; kt++){
      // A rows replicated: row m -> h[m&1]; h scaled x16
      unsigned long long a = *(const unsigned long long*)&hist[tl][l15 & 1][kt * 32 + lq * 8];
      #pragma unroll
      for (int nl = 0; nl < 8; nl++)
        racc[nl] = __builtin_amdgcn_mfma_f32_16x16x32_fp8_fp8(
            (long long)a, (long long)wfr[nl][kt], racc[nl], 0, 0, 0);
    }
    // gates for rows (br=0,1) = D rows 0,1 (lq==0 lanes); xg rows 2tl,2tl+1 via shfl
    #pragma unroll
    for (int nl = 0; nl < 8; nl++){
      const int e0 = (2 * tl) & 3;
      const int srcl = l15 + ((tl >> 1) << 4);
      float x0 = __shfl(xga[nl][e0],     srcl, 64);
      float x1 = __shfl(xga[nl][e0 + 1], srcl, 64);
      if (lq == 0){
        float2 g;
        g.x = racc[nl][0] * 0.0078125f + x0;   // /(16*8)
        g.y = racc[nl][1] * 0.0078125f + x1;
        *(float2*)&gbuf[(w * 8 + nl) * 16 + l15][0] = g;
      }
    }
    __syncthreads();
    {
      float iv = gbuf[      sq][srow];
      float fv = gbuf[256 + sq][srow];
      float gv = gbuf[512 + sq][srow];
      float ov = gbuf[768 + sq][srow];
      float cn = sigmoidf_(fv) * creg + sigmoidf_(iv) * tanhf_(gv);
      creg = cn;
      float hv = sigmoidf_(ov) * tanhf_(cn);
      int p8 = __builtin_amdgcn_cvt_pk_fp8_f32(hv * 16.f, 0.f, 0, false);
      hist[tl + 1][srow][sq] = (unsigned char)(p8 & 0xff);
    }
    __syncthreads();
  }

  // pred: rows ra=l15 -> h(t0+ra>>1) ; write fp8 ring (pred*8)
  #pragma unroll
  for (int i = 0; i < 2; i++){
    int ntp = w * 2 + i;
    f32x4 pacc = (f32x4){0.f, 0.f, 0.f, 0.f};
    const unsigned long long* bsrc = wpf + (size_t)mod * 8192 + ntp * 512 + lane;
    #pragma unroll
    for (int kt = 0; kt < 8; kt++){
      unsigned long long a = *(const unsigned long long*)&hist[(l15 >> 1) + 1][l15 & 1][kt * 32 + lq * 8];
      pacc = __builtin_amdgcn_mfma_f32_16x16x32_fp8_fp8(
          (long long)a, (long long)bsrc[kt * 64], pacc, 0, 0, 0);
    }
    int col = ntp * 16 + l15;
    float bp8 = 8.f * bpsel[col];
    #pragma unroll
    for (int r = 0; r < 4; r++){
      int ra = lq * 4 + r;
      int tg = t0 + (ra >> 1);
      int wi = tg - 1;
      if (wi >= 0 && wi < NW){
        float val = pacc[r] * 0.0625f + bp8;   // (h16@Wp8)/128*8 + 8*bp
        int p8 = __builtin_amdgcn_cvt_pk_fp8_f32(val, 0.f, 0, false);
        ring[(((size_t)(wi & 7) * 3 + mod) * 128 + (b0 + (ra & 1))) * 256 + col] =
            (unsigned char)(p8 & 0xff);
      }
    }
  }

  // persist state
  hstate[((size_t)mod * 128 + b0 + srow) * 256 + sq] = hist[8][srow][sq];
  cstate[((size_t)mod * 128 + b0 + srow) * 256 + sq] = creg;
}

// ---------------- fused pair kernel ----------------
__global__ __launch_bounds__(256, 1) void k_pair(
    const float* xv, const float* xa, const float* xt,
    const unsigned char* ring, const int* lengths,
    float* nce_acc, float* hits_acc, int wbase)
{
  const int w = wbase + blockIdx.x;
  const int j = blockIdx.y;
  const int encm_[9] = {1, 1, 0, 0, 2, 2, 1, 0, 2};
  const int prdm_[9] = {0, 2, 2, 1, 1, 0, 1, 0, 2};
  const float wj_[9] = {1.f, 1.f, 1.f, 1.f, 1.f, 1.f, 0.1f, 0.1f, 0.1f};
  __shared__ __align__(16) unsigned char smem[135168];
  unsigned short (*encs)[264] = (unsigned short (*)[264])smem;
  unsigned short (*prds)[264] = (unsigned short (*)[264])(smem + 67584);
  float (*S)[132] = (float (*)[132])smem;  // overlays encs after MFMA
  __shared__ unsigned char maskb[128];
  __shared__ float rcp_s[128];
  __shared__ float redb[8];
  const int tid = threadIdx.x;
  const int wid = tid >> 6, lane = tid & 63;
  const int l15 = lane & 15, lq = lane >> 4;
  const int em = encm_[j], pm = prdm_[j];
  const float* xs = (em == 0) ? xv : ((em == 1) ? xa : xt);

  {
    const int row = tid >> 1, half = tid & 1;
    const float* ps = xs + ((size_t)row * 256 + (w + 2)) * 256 + half * 128;
    for (int q = 0; q < 32; q++){
      float4 v = *(const float4*)(ps + q * 4);
      __align__(8) unsigned short t4[4] = {f2bf(v.x), f2bf(v.y), f2bf(v.z), f2bf(v.w)};
      *(unsigned long long*)&encs[row][half * 128 + q * 4] = *(unsigned long long*)t4;
    }
    const unsigned char* pp = ring + (((size_t)(w & 7) * 3 + pm) * 128 + row) * 256 + half * 128;
    #pragma unroll
    for (int q = 0; q < 8; q++){
      uint4 rw = *(const uint4*)(pp + q * 16);
      unsigned int wds[4] = {rw.x, rw.y, rw.z, rw.w};
      __align__(16) unsigned short o[16];
      #pragma unroll
      for (int u = 0; u < 4; u++)
        #pragma unroll
        for (int b = 0; b < 4; b++){
          float f = fp8_to_f32((wds[u] >> (8 * b)) & 0xffu) * 0.125f;
          o[u * 4 + b] = f2bf(f);
        }
      *(uint4*)&prds[row][half * 128 + q * 16]     = *(uint4*)&o[0];
      *(uint4*)&prds[row][half * 128 + q * 16 + 8] = *(uint4*)&o[8];
    }
    if (tid < 128) maskb[tid] = (lengths[tid] > (w + 2)) ? 1 : 0;
  }
  __syncthreads();

  f32x4 acc[2][8];
  #pragma unroll
  for (int a = 0; a < 2; a++)
    #pragma unroll
    for (int b = 0; b < 8; b++)
      acc[a][b] = (f32x4){0.f, 0.f, 0.f, 0.f};
  for (int kt = 0; kt < 8; kt++){
    bf16x8 af[2], bfr[8];
    #pragma unroll
    for (int mt = 0; mt < 2; mt++)
      af[mt] = *(const bf16x8*)&encs[(wid * 2 + mt) * 16 + l15][kt * 32 + lq * 8];
    #pragma unroll
    for (int nt = 0; nt < 8; nt++)
      bfr[nt] = *(const bf16x8*)&prds[nt * 16 + l15][kt * 32 + lq * 8];
    #pragma unroll
    for (int mt = 0; mt < 2; mt++)
      #pragma unroll
      for (int nt = 0; nt < 8; nt++)
        acc[mt][nt] = __builtin_amdgcn_mfma_f32_16x16x32_bf16(af[mt], bfr[nt], acc[mt][nt], 0, 0, 0);
  }
  __syncthreads();
  #pragma unroll
  for (int mt = 0; mt < 2; mt++)
    #pragma unroll
    for (int nt = 0; nt < 8; nt++)
      #pragma unroll
      for (int r = 0; r < 4; r++){
        int rowg = (wid * 2 + mt) * 16 + lq * 4 + r;
        int col = nt * 16 + l15;
        S[rowg][col] = acc[mt][nt][r];
      }
  __syncthreads();

  float nce_local = 0.f;
  if (tid < 128 && maskb[tid]){
    int r = tid;
    float m = -1e30f;
    for (int cc = 0; cc < 128; cc++)
      if (maskb[cc]) m = fmaxf(m, S[r][cc]);
    float srr = S[r][r];
    float s = 0.f;
    for (int cc = 0; cc < 128; cc++){
      if (maskb[cc]){
        float e = __expf(S[r][cc] - m);
        s += e;
        S[r][cc] = e;
      }
    }
    rcp_s[r] = 1.0f / s;
    nce_local = srr - m - __logf(s);
  }
  float v1 = nce_local;
  #pragma unroll
  for (int off = 32; off > 0; off >>= 1) v1 += __shfl_down(v1, off, 64);
  if (lane == 0) redb[wid] = v1;
  __syncthreads();
  if (tid == 0){
    float tot = redb[0] + redb[1] + redb[2] + redb[3];
    if (tot != 0.f) atomicAdd(&nce_acc[w], wj_[j] * tot);
  }

  int hit = 0;
  if (tid < 128 && maskb[tid]){
    int cl = tid;
    float best = -1.f; int arg = -1;
    for (int r = 0; r < 128; r++){
      if (maskb[r]){
        float v = S[r][cl] * rcp_s[r];
        if (v > best){ best = v; arg = r; }
      }
    }
    hit = (arg == cl) ? 1 : 0;
  }
  float v2 = (float)hit;
  #pragma unroll
  for (int off = 32; off > 0; off >>= 1) v2 += __shfl_down(v2, off, 64);
  if (lane == 0) redb[4 + wid] = v2;
  __syncthreads();
  if (tid == 0){
    float tot = redb[4] + redb[5] + redb[6] + redb[7];
    if (tot != 0.f) atomicAdd(&hits_acc[(size_t)j * NW + w], tot);
  }
}

// ---------------- final reduction ----------------
__global__ void k_final(const int* lengths, const float* nce_acc, const float* hits_acc, float* out){
  __shared__ float red[256];
  int tid = threadIdx.x;
  float nw_l = 0.f, nce_l = 0.f;
  float acc_l[9];
  #pragma unroll
  for (int q = 0; q < 9; q++) acc_l[q] = 0.f;
  if (tid < NW){
    int vc = 0;
    for (int b = 0; b < 128; b++) vc += (lengths[b] > (tid + 2)) ? 1 : 0;
    if (vc > 0){
      float safe = (float)vc;
      nw_l = 1.f;
      nce_l = nce_acc[tid] / (-safe);
      for (int q = 0; q < 9; q++) acc_l[q] = hits_acc[q * NW + tid] / safe;
    }
  }
  float vals[11];
  vals[0] = nw_l; vals[1] = nce_l;
  for (int q = 0; q < 9; q++) vals[2 + q] = acc_l[q];
  float sums[11];
  for (int s = 0; s < 11; s++){
    red[tid] = vals[s];
    __syncthreads();
    for (int off = 128; off > 0; off >>= 1){
      if (tid < off) red[tid] += red[tid + off];
      __syncthreads();
    }
    sums[s] = red[0];
    __syncthreads();
  }
  if (tid == 0){
    float nwin = fmaxf(sums[0], 1.f);
    for (int q = 0; q < 9; q++) out[q] = sums[2 + q] / nwin;
    out[9] = sums[1] / nwin;
  }
}

// ---------------- launch ----------------
extern "C" void kernel_launch(void* const* d_in, const int* in_sizes, int n_in,
                              void* d_out, int out_size, void* d_ws, size_t ws_size,
                              hipStream_t stream)
{
  const float* audio = (const float*)d_in[0];
  const float* video = (const float*)d_in[1];
  const float* text  = (const float*)d_in[2];
  const float* vWih = (const float*)d_in[3];
  const float* vWhh = (const float*)d_in[4];
  const float* vbih = (const float*)d_in[5];
  const float* vbhh = (const float*)d_in[6];
  const float* aWih = (const float*)d_in[7];
  const float* aWhh = (const float*)d_in[8];
  const float* abih = (const float*)d_in[9];
  const float* abhh = (const float*)d_in[10];
  const float* tWih = (const float*)d_in[11];
  const float* tWhh = (const float*)d_in[12];
  const float* tbih = (const float*)d_in[13];
  const float* tbhh = (const float*)d_in[14];
  const float* vWp = (const float*)d_in[15];
  const float* vbp = (const float*)d_in[16];
  const float* aWp = (const float*)d_in[17];
  const float* abp = (const float*)d_in[18];
  const float* tWp = (const float*)d_in[19];
  const float* tbp = (const float*)d_in[20];
  const int* lengths = (const int*)d_in[21];

  // ---- tiny workspace layout (total 3,069,952 B <= 3 MiB) ----
  char* ws = (char*)d_ws;
  unsigned long long* wihf = (unsigned long long*)(ws);             // 786,432
  unsigned long long* whhf = (unsigned long long*)(ws + 786432);    // 786,432
  unsigned long long* wpf  = (unsigned long long*)(ws + 1572864);   // 196,608
  float* biasc             = (float*)(ws + 1769472);                //  12,288
  float* cstate            = (float*)(ws + 1781760);                // 393,216
  unsigned char* hstate    = (unsigned char*)(ws + 2174976);        //  98,304
  unsigned char* ring      = (unsigned char*)(ws + 2273280);        // 786,432
  float* nce_acc           = (float*)(ws + 3059712);                //  10,160
  float* hits_acc          = nce_acc + NW;

  if (ws_size < 3069952ull){
    // report ws_size (MB) + 200 via outputs
    k_diag<<<1, 64, 0, stream>>>((float*)d_out, 200.0f + (float)(ws_size >> 20));
    return;
  }

  hipMemsetAsync(nce_acc, 0, 10 * NW * sizeof(float), stream);

  k_wcvt<<<384, 256, 0, stream>>>(vWih, aWih, tWih, wihf, 64);
  k_wcvt<<<384, 256, 0, stream>>>(vWhh, aWhh, tWhh, whhf, 64);
  k_wcvt<<<96,  256, 0, stream>>>(vWp,  aWp,  tWp,  wpf,  16);
  k_bias<<<12, 256, 0, stream>>>(vbih, vbhh, abih, abhh, tbih, tbhh, biasc);

  for (int c = 0; c < 32; c++){
    k_lstm<<<192, 512, 0, stream>>>(wihf, whhf, wpf, biasc,
                                    video, audio, text,
                                    vbp, abp, tbp,
                                    cstate, hstate, ring, 8 * c);
    int wb = 8 * c - 1, nw = 8;
    if (c == 0) { wb = 0; nw = 7; }
    if (c == 31) nw = 7;
    k_pair<<<dim3(nw, 9), 256, 0, stream>>>(video, audio, text, ring, lengths,
                                            nce_acc, hits_acc, wb);
  }

  k_final<<<1, 256, 0, stream>>>(lengths, nce_acc, hits_acc, (float*)d_out);
}

// Round 7
// 1537.242 us; speedup vs baseline: 1.4707x; 1.4707x over previous
//
#include <hip/hip_runtime.h>
#include <stdint.h>

#define NW 254

typedef float f32x4 __attribute__((ext_vector_type(4)));
typedef __bf16 bf16x8 __attribute__((ext_vector_type(8)));

__device__ __forceinline__ unsigned short f2bf(float f){
  union { float f; unsigned int i; } v; v.f = f;
  unsigned int r = (v.i + 0x7FFFu + ((v.i >> 16) & 1u)) >> 16;
  return (unsigned short)r;
}
__device__ __forceinline__ float sigmoidf_(float x){ return 1.0f / (1.0f + __expf(-x)); }
__device__ __forceinline__ float tanhf_(float x){ return 1.0f - 2.0f / (__expf(2.0f * x) + 1.0f); }

__device__ __forceinline__ float fp8_to_f32(unsigned int b){
#if __has_builtin(__builtin_amdgcn_cvt_f32_fp8)
  return __builtin_amdgcn_cvt_f32_fp8(b, 0);
#else
  unsigned int s = b >> 7, e = (b >> 3) & 15, m = b & 7;
  float v;
  if (e == 0) v = (float)m * 0.001953125f;
  else        v = ldexpf((float)(8 + m), (int)e - 10);
  return s ? -v : v;
#endif
}

// ---------------- diagnostic ----------------
__global__ void k_diag(float* out, float v){
  if (threadIdx.x < 10) out[threadIdx.x] = v;
}

// ---------------- prep: W[N,256] f32 -> fp8 frags x8 scale ----------------
// dst[mod][nt][kt][lane] u64; byte j = fp8(8*W[nt*16+(l&15)][kt*32+(l>>4)*8+j])
__global__ void k_wcvt(const float* W0, const float* W1, const float* W2,
                       unsigned long long* dst, int NT){
  int gid = blockIdx.x * 256 + threadIdx.x;
  int per_mod = NT * 8 * 64;
  int mod = gid / per_mod;
  if (mod >= 3) return;
  int r = gid % per_mod;
  int nt = r / 512; int r2 = r % 512;
  int kt = r2 >> 6; int lane = r2 & 63;
  const float* W = (mod == 0) ? W0 : ((mod == 1) ? W1 : W2);
  int n = nt * 16 + (lane & 15);
  int k = kt * 32 + (lane >> 4) * 8;
  const float* p = W + (size_t)n * 256 + k;
  int lo = __builtin_amdgcn_cvt_pk_fp8_f32(8.f*p[0], 8.f*p[1], 0, false);
  lo     = __builtin_amdgcn_cvt_pk_fp8_f32(8.f*p[2], 8.f*p[3], lo, true);
  int hi = __builtin_amdgcn_cvt_pk_fp8_f32(8.f*p[4], 8.f*p[5], 0, false);
  hi     = __builtin_amdgcn_cvt_pk_fp8_f32(8.f*p[6], 8.f*p[7], hi, true);
  dst[gid] = ((unsigned long long)(unsigned int)hi << 32) | (unsigned int)lo;
}

__global__ void k_bias(const float* v1, const float* v2, const float* a1, const float* a2,
                       const float* t1, const float* t2, float* dst){
  int gid = blockIdx.x * 256 + threadIdx.x;
  if (gid >= 3072) return;
  int mod = gid >> 10, n = gid & 1023;
  const float* p1 = (mod == 0) ? v1 : ((mod == 1) ? a1 : t1);
  const float* p2 = (mod == 0) ? v2 : ((mod == 1) ? a2 : t2);
  dst[gid] = p1[n] + p2[n];
}

// ---------------- fused xg + LSTM + pred (chunk of 8 steps) ----------------
// 192 blocks: mod = blk>>6, row-pair rp = blk&63 (batch rows 2rp, 2rp+1).
// Whh fp8 frags VGPR-resident; xg computed in-registers; pred -> fp8 ring.
__global__ __launch_bounds__(512, 1) void k_lstm(
    const unsigned long long* wihf, const unsigned long long* whhf,
    const unsigned long long* wpf, const float* biasg,
    const float* xv, const float* xa, const float* xt,
    const float* bpv, const float* bpa, const float* bpt,
    float* cstate, unsigned char* hstate, unsigned char* ring, int t0)
{
  const int blk = blockIdx.x;
  const int mod = blk >> 6;
  const int b0  = (blk & 63) * 2;
  const int tid = threadIdx.x;
  const int w   = tid >> 6;
  const int lane = tid & 63;
  const int l15 = lane & 15, lq = lane >> 4;

  __shared__ __align__(16) unsigned char hist[9][2][256];  // h*16 fp8, hist[0]=carry-in
  __shared__ __align__(16) float gbuf[1024][2];

  const float* xsel  = (mod == 0) ? xv  : ((mod == 1) ? xa  : xt);
  const float* bpsel = (mod == 0) ? bpv : ((mod == 1) ? bpa : bpt);

  // state init (thread owns (row=tid>>8, q=tid&255))
  const int srow = tid >> 8, sq = tid & 255;
  hist[0][srow][sq] = (t0 == 0) ? (unsigned char)0
      : hstate[((size_t)mod * 128 + b0 + srow) * 256 + sq];
  float creg = (t0 == 0) ? 0.f
      : cstate[((size_t)mod * 128 + b0 + srow) * 256 + sq];

  // Whh frags resident: wave w owns gate cols [128w, 128w+128)
  unsigned long long wfr[8][8];
  {
    const unsigned long long* src = whhf + (size_t)mod * 32768 + w * 4096 + lane;
    #pragma unroll
    for (int nl = 0; nl < 8; nl++)
      #pragma unroll
      for (int kt = 0; kt < 8; kt++)
        wfr[nl][kt] = src[(nl * 8 + kt) * 64];
  }

  // A-frags for xg: row ra=l15 -> (tl=ra>>1, br=ra&1); x fp8 unscaled
  unsigned long long afr[8];
  {
    const float* xp = xsel + ((size_t)(b0 + (l15 & 1)) * 256 + (t0 + (l15 >> 1))) * 256;
    #pragma unroll
    for (int kt = 0; kt < 8; kt++){
      float4 va = *(const float4*)(xp + kt * 32 + lq * 8);
      float4 vb = *(const float4*)(xp + kt * 32 + lq * 8 + 4);
      int lo = __builtin_amdgcn_cvt_pk_fp8_f32(va.x, va.y, 0, false);
      lo     = __builtin_amdgcn_cvt_pk_fp8_f32(va.z, va.w, lo, true);
      int hi = __builtin_amdgcn_cvt_pk_fp8_f32(vb.x, vb.y, 0, false);
      hi     = __builtin_amdgcn_cvt_pk_fp8_f32(vb.z, vb.w, hi, true);
      afr[kt] = ((unsigned long long)(unsigned int)hi << 32) | (unsigned int)lo;
    }
  }

  // xg GEMM: xga[nl][r] = XG[row=lq*4+r][col=(w*8+nl)*16+l15] (scaled back, +bias)
  f32x4 xga[8];
  {
    const unsigned long long* bsrc = wihf + (size_t)mod * 32768 + w * 4096 + lane;
    #pragma unroll
    for (int nl = 0; nl < 8; nl++){
      f32x4 acc = (f32x4){0.f, 0.f, 0.f, 0.f};
      #pragma unroll
      for (int kt = 0; kt < 8; kt++)
        acc = __builtin_amdgcn_mfma_f32_16x16x32_fp8_fp8(
            (long long)afr[kt], (long long)bsrc[(nl * 8 + kt) * 64], acc, 0, 0, 0);
      float bg = biasg[mod * 1024 + (w * 8 + nl) * 16 + l15];
      #pragma unroll
      for (int r = 0; r < 4; r++) xga[nl][r] = acc[r] * 0.125f + bg;
    }
  }
  __syncthreads();  // hist[0] ready

  // recurrence: 8 steps
  #pragma unroll
  for (int tl = 0; tl < 8; tl++){
    f32x4 racc[8];
    #pragma unroll
    for (int nl = 0; nl < 8; nl++) racc[nl] = (f32x4){0.f, 0.f, 0.f, 0.f};
    #pragma unroll
    for (int kt = 0; kt < 8; kt++){
      // A rows replicated: row m -> h[m&1]; h scaled x16
      unsigned long long a = *(const unsigned long long*)&hist[tl][l15 & 1][kt * 32 + lq * 8];
      #pragma unroll
      for (int nl = 0; nl < 8; nl++)
        racc[nl] = __builtin_amdgcn_mfma_f32_16x16x32_fp8_fp8(
            (long long)a, (long long)wfr[nl][kt], racc[nl], 0, 0, 0);
    }
    // gates for rows (br=0,1) = D rows 0,1 (lq==0 lanes); xg rows 2tl,2tl+1 via shfl
    #pragma unroll
    for (int nl = 0; nl < 8; nl++){
      const int e0 = (2 * tl) & 3;
      const int srcl = l15 + ((tl >> 1) << 4);
      float x0 = __shfl(xga[nl][e0],     srcl, 64);
      float x1 = __shfl(xga[nl][e0 + 1], srcl, 64);
      if (lq == 0){
        float2 g;
        g.x = racc[nl][0] * 0.0078125f + x0;   // /(16*8)
        g.y = racc[nl][1] * 0.0078125f + x1;
        *(float2*)&gbuf[(w * 8 + nl) * 16 + l15][0] = g;
      }
    }
    __syncthreads();
    {
      float iv = gbuf[      sq][srow];
      float fv = gbuf[256 + sq][srow];
      float gv = gbuf[512 + sq][srow];
      float ov = gbuf[768 + sq][srow];
      float cn = sigmoidf_(fv) * creg + sigmoidf_(iv) * tanhf_(gv);
      creg = cn;
      float hv = sigmoidf_(ov) * tanhf_(cn);
      int p8 = __builtin_amdgcn_cvt_pk_fp8_f32(hv * 16.f, 0.f, 0, false);
      hist[tl + 1][srow][sq] = (unsigned char)(p8 & 0xff);
    }
    __syncthreads();
  }

  // pred: rows ra=l15 -> h(t0+ra>>1) ; write fp8 ring (pred*8)
  #pragma unroll
  for (int i = 0; i < 2; i++){
    int ntp = w * 2 + i;
    f32x4 pacc = (f32x4){0.f, 0.f, 0.f, 0.f};
    const unsigned long long* bsrc = wpf + (size_t)mod * 8192 + ntp * 512 + lane;
    #pragma unroll
    for (int kt = 0; kt < 8; kt++){
      unsigned long long a = *(const unsigned long long*)&hist[(l15 >> 1) + 1][l15 & 1][kt * 32 + lq * 8];
      pacc = __builtin_amdgcn_mfma_f32_16x16x32_fp8_fp8(
          (long long)a, (long long)bsrc[kt * 64], pacc, 0, 0, 0);
    }
    int col = ntp * 16 + l15;
    float bp8 = 8.f * bpsel[col];
    #pragma unroll
    for (int r = 0; r < 4; r++){
      int ra = lq * 4 + r;
      int tg = t0 + (ra >> 1);
      int wi = tg - 1;
      if (wi >= 0 && wi < NW){
        float val = pacc[r] * 0.0625f + bp8;   // (h16@Wp8)/128*8 + 8*bp
        int p8 = __builtin_amdgcn_cvt_pk_fp8_f32(val, 0.f, 0, false);
        ring[(((size_t)(wi & 7) * 3 + mod) * 128 + (b0 + (ra & 1))) * 256 + col] =
            (unsigned char)(p8 & 0xff);
      }
    }
  }

  // persist state
  hstate[((size_t)mod * 128 + b0 + srow) * 256 + sq] = hist[8][srow][sq];
  cstate[((size_t)mod * 128 + b0 + srow) * 256 + sq] = creg;
}

// ---------------- fused pair kernel ----------------
__global__ __launch_bounds__(256, 1) void k_pair(
    const float* xv, const float* xa, const float* xt,
    const unsigned char* ring, const int* lengths,
    float* nce_acc, float* hits_acc, int wbase)
{
  const int w = wbase + blockIdx.x;
  const int j = blockIdx.y;
  const int encm_[9] = {1, 1, 0, 0, 2, 2, 1, 0, 2};
  const int prdm_[9] = {0, 2, 2, 1, 1, 0, 1, 0, 2};
  const float wj_[9] = {1.f, 1.f, 1.f, 1.f, 1.f, 1.f, 0.1f, 0.1f, 0.1f};
  __shared__ __align__(16) unsigned char smem[135168];
  unsigned short (*encs)[264] = (unsigned short (*)[264])smem;
  unsigned short (*prds)[264] = (unsigned short (*)[264])(smem + 67584);
  float (*S)[132] = (float (*)[132])smem;  // overlays encs after MFMA
  __shared__ unsigned char maskb[128];
  __shared__ float rcp_s[128];
  __shared__ float redb[8];
  const int tid = threadIdx.x;
  const int wid = tid >> 6, lane = tid & 63;
  const int l15 = lane & 15, lq = lane >> 4;
  const int em = encm_[j], pm = prdm_[j];
  const float* xs = (em == 0) ? xv : ((em == 1) ? xa : xt);

  {
    const int row = tid >> 1, half = tid & 1;
    const float* ps = xs + ((size_t)row * 256 + (w + 2)) * 256 + half * 128;
    #pragma unroll
    for (int q = 0; q < 32; q++){
      float4 v = *(const float4*)(ps + q * 4);
      __align__(8) unsigned short t4[4] = {f2bf(v.x), f2bf(v.y), f2bf(v.z), f2bf(v.w)};
      *(unsigned long long*)&encs[row][half * 128 + q * 4] = *(unsigned long long*)t4;
    }
    const unsigned char* pp = ring + (((size_t)(w & 7) * 3 + pm) * 128 + row) * 256 + half * 128;
    #pragma unroll
    for (int q = 0; q < 8; q++){
      uint4 rw = *(const uint4*)(pp + q * 16);
      unsigned int wds[4] = {rw.x, rw.y, rw.z, rw.w};
      __align__(16) unsigned short o[16];
      #pragma unroll
      for (int u = 0; u < 4; u++)
        #pragma unroll
        for (int b = 0; b < 4; b++){
          float f = fp8_to_f32((wds[u] >> (8 * b)) & 0xffu) * 0.125f;
          o[u * 4 + b] = f2bf(f);
        }
      *(uint4*)&prds[row][half * 128 + q * 16]     = *(uint4*)&o[0];
      *(uint4*)&prds[row][half * 128 + q * 16 + 8] = *(uint4*)&o[8];
    }
    if (tid < 128) maskb[tid] = (lengths[tid] > (w + 2)) ? 1 : 0;
  }
  __syncthreads();

  f32x4 acc[2][8];
  #pragma unroll
  for (int a = 0; a < 2; a++)
    #pragma unroll
    for (int b = 0; b < 8; b++)
      acc[a][b] = (f32x4){0.f, 0.f, 0.f, 0.f};
  for (int kt = 0; kt < 8; kt++){
    bf16x8 af[2], bfr[8];
    #pragma unroll
    for (int mt = 0; mt < 2; mt++)
      af[mt] = *(const bf16x8*)&encs[(wid * 2 + mt) * 16 + l15][kt * 32 + lq * 8];
    #pragma unroll
    for (int nt = 0; nt < 8; nt++)
      bfr[nt] = *(const bf16x8*)&prds[nt * 16 + l15][kt * 32 + lq * 8];
    #pragma unroll
    for (int mt = 0; mt < 2; mt++)
      #pragma unroll
      for (int nt = 0; nt < 8; nt++)
        acc[mt][nt] = __builtin_amdgcn_mfma_f32_16x16x32_bf16(af[mt], bfr[nt], acc[mt][nt], 0, 0, 0);
  }
  __syncthreads();
  // store scores pre-masked: invalid columns -> -1e9 (branch-free softmax below)
  #pragma unroll
  for (int mt = 0; mt < 2; mt++)
    #pragma unroll
    for (int nt = 0; nt < 8; nt++){
      int col = nt * 16 + l15;
      float mk = maskb[col] ? 0.f : -1e9f;
      #pragma unroll
      for (int r = 0; r < 4; r++){
        int rowg = (wid * 2 + mt) * 16 + lq * 4 + r;
        S[rowg][col] = acc[mt][nt][r] + mk;
      }
    }
  __syncthreads();

  // row softmax: fully unrolled float4 LDS passes, no branches in loops
  float nce_local = 0.f;
  if (tid < 128){
    if (maskb[tid]){
      float* Sr = &S[tid][0];
      float m = -1e30f;
      #pragma unroll
      for (int cc = 0; cc < 128; cc += 4){
        float4 v = *(const float4*)(Sr + cc);
        m = fmaxf(m, fmaxf(fmaxf(v.x, v.y), fmaxf(v.z, v.w)));
      }
      float srr = Sr[tid];
      float s = 0.f;
      #pragma unroll
      for (int cc = 0; cc < 128; cc += 4){
        float4 v = *(const float4*)(Sr + cc);
        v.x = __expf(v.x - m); v.y = __expf(v.y - m);
        v.z = __expf(v.z - m); v.w = __expf(v.w - m);
        s += (v.x + v.y) + (v.z + v.w);
        *(float4*)(Sr + cc) = v;
      }
      rcp_s[tid] = 1.0f / s;
      nce_local = srr - m - __logf(s);
    } else {
      rcp_s[tid] = 0.f;   // kills invalid rows in argmax below
    }
  }
  float v1 = nce_local;
  #pragma unroll
  for (int off = 32; off > 0; off >>= 1) v1 += __shfl_down(v1, off, 64);
  if (lane == 0) redb[wid] = v1;
  __syncthreads();
  if (tid == 0){
    float tot = redb[0] + redb[1] + redb[2] + redb[3];
    if (tot != 0.f) atomicAdd(&nce_acc[w], wj_[j] * tot);
  }

  // column argmax over rows (branch-free; invalid rows give v = 0)
  int hit = 0;
  if (tid < 128 && maskb[tid]){
    int cl = tid;
    float best = 0.f; int arg = -1;
    #pragma unroll 16
    for (int r = 0; r < 128; r++){
      float v = S[r][cl] * rcp_s[r];
      if (v > best){ best = v; arg = r; }
    }
    hit = (arg == cl) ? 1 : 0;
  }
  float v2 = (float)hit;
  #pragma unroll
  for (int off = 32; off > 0; off >>= 1) v2 += __shfl_down(v2, off, 64);
  if (lane == 0) redb[4 + wid] = v2;
  __syncthreads();
  if (tid == 0){
    float tot = redb[4] + redb[5] + redb[6] + redb[7];
    if (tot != 0.f) atomicAdd(&hits_acc[(size_t)j * NW + w], tot);
  }
}

// ---------------- final reduction ----------------
__global__ void k_final(const int* lengths, const float* nce_acc, const float* hits_acc, float* out){
  __shared__ float red[256];
  int tid = threadIdx.x;
  float nw_l = 0.f, nce_l = 0.f;
  float acc_l[9];
  #pragma unroll
  for (int q = 0; q < 9; q++) acc_l[q] = 0.f;
  if (tid < NW){
    int vc = 0;
    for (int b = 0; b < 128; b++) vc += (lengths[b] > (tid + 2)) ? 1 : 0;
    if (vc > 0){
      float safe = (float)vc;
      nw_l = 1.f;
      nce_l = nce_acc[tid] / (-safe);
      for (int q = 0; q < 9; q++) acc_l[q] = hits_acc[q * NW + tid] / safe;
    }
  }
  float vals[11];
  vals[0] = nw_l; vals[1] = nce_l;
  for (int q = 0; q < 9; q++) vals[2 + q] = acc_l[q];
  float sums[11];
  for (int s = 0; s < 11; s++){
    red[tid] = vals[s];
    __syncthreads();
    for (int off = 128; off > 0; off >>= 1){
      if (tid < off) red[tid] += red[tid + off];
      __syncthreads();
    }
    sums[s] = red[0];
    __syncthreads();
  }
  if (tid == 0){
    float nwin = fmaxf(sums[0], 1.f);
    for (int q = 0; q < 9; q++) out[q] = sums[2 + q] / nwin;
    out[9] = sums[1] / nwin;
  }
}

// ---------------- launch ----------------
extern "C" void kernel_launch(void* const* d_in, const int* in_sizes, int n_in,
                              void* d_out, int out_size, void* d_ws, size_t ws_size,
                              hipStream_t stream)
{
  const float* audio = (const float*)d_in[0];
  const float* video = (const float*)d_in[1];
  const float* text  = (const float*)d_in[2];
  const float* vWih = (const float*)d_in[3];
  const float* vWhh = (const float*)d_in[4];
  const float* vbih = (const float*)d_in[5];
  const float* vbhh = (const float*)d_in[6];
  const float* aWih = (const float*)d_in[7];
  const float* aWhh = (const float*)d_in[8];
  const float* abih = (const float*)d_in[9];
  const float* abhh = (const float*)d_in[10];
  const float* tWih = (const float*)d_in[11];
  const float* tWhh = (const float*)d_in[12];
  const float* tbih = (const float*)d_in[13];
  const float* tbhh = (const float*)d_in[14];
  const float* vWp = (const float*)d_in[15];
  const float* vbp = (const float*)d_in[16];
  const float* aWp = (const float*)d_in[17];
  const float* abp = (const float*)d_in[18];
  const float* tWp = (const float*)d_in[19];
  const float* tbp = (const float*)d_in[20];
  const int* lengths = (const int*)d_in[21];

  // ---- tiny workspace layout (total 3,069,952 B <= 3 MiB) ----
  char* ws = (char*)d_ws;
  unsigned long long* wihf = (unsigned long long*)(ws);             // 786,432
  unsigned long long* whhf = (unsigned long long*)(ws + 786432);    // 786,432
  unsigned long long* wpf  = (unsigned long long*)(ws + 1572864);   // 196,608
  float* biasc             = (float*)(ws + 1769472);                //  12,288
  float* cstate            = (float*)(ws + 1781760);                // 393,216
  unsigned char* hstate    = (unsigned char*)(ws + 2174976);        //  98,304
  unsigned char* ring      = (unsigned char*)(ws + 2273280);        // 786,432
  float* nce_acc           = (float*)(ws + 3059712);                //  10,160
  float* hits_acc          = nce_acc + NW;

  if (ws_size < 3069952ull){
    // report ws_size (MB) + 200 via outputs
    k_diag<<<1, 64, 0, stream>>>((float*)d_out, 200.0f + (float)(ws_size >> 20));
    return;
  }

  hipMemsetAsync(nce_acc, 0, 10 * NW * sizeof(float), stream);

  k_wcvt<<<384, 256, 0, stream>>>(vWih, aWih, tWih, wihf, 64);
  k_wcvt<<<384, 256, 0, stream>>>(vWhh, aWhh, tWhh, whhf, 64);
  k_wcvt<<<96,  256, 0, stream>>>(vWp,  aWp,  tWp,  wpf,  16);
  k_bias<<<12, 256, 0, stream>>>(vbih, vbhh, abih, abhh, tbih, tbhh, biasc);

  for (int c = 0; c < 32; c++){
    k_lstm<<<192, 512, 0, stream>>>(wihf, whhf, wpf, biasc,
                                    video, audio, text,
                                    vbp, abp, tbp,
                                    cstate, hstate, ring, 8 * c);
    int wb = 8 * c - 1, nw = 8;
    if (c == 0) { wb = 0; nw = 7; }
    if (c == 31) nw = 7;
    k_pair<<<dim3(nw, 9), 256, 0, stream>>>(video, audio, text, ring, lengths,
                                            nce_acc, hits_acc, wb);
  }

  k_final<<<1, 256, 0, stream>>>(lengths, nce_acc, hits_acc, (float*)d_out);
}